// Round 10
// baseline (140.059 us; speedup 1.0000x reference)
//
#include <hip/hip_runtime.h>
#include <math.h>

// B=8, T=2048, C=1024, H=64. bf16 MFMA proj + staged split-KV flash attention.
namespace {
constexpr int BATCH = 8;
constexpr int TSEQ  = 2048;
constexpr int CDIM  = 1024;
constexpr int HDIM  = 64;
constexpr int MROWS = BATCH * TSEQ;         // 16384
constexpr int NTILE = 128;                  // 16-row q-tiles per batch
constexpr int NSLC  = 8;                    // KV slices per q-tile
// fold softmax scale (1/8) AND log2(e) into Wq so softmax can use exp2
constexpr float QSCALE = 0.125f * 1.4426950408889634f;
}

typedef __attribute__((ext_vector_type(4))) float  f32x4;
typedef __attribute__((ext_vector_type(8))) short  s16x8;   // 8 bf16 (4 VGPRs)
typedef __attribute__((ext_vector_type(4))) unsigned short u16x4;

__device__ __forceinline__ unsigned short f2bf(float f) {
    union { float f; unsigned u; } c{f};
    unsigned r = c.u + 0x7FFFu + ((c.u >> 16) & 1u);   // RNE
    return (unsigned short)(r >> 16);
}

// ---------------------------------------------------------------------------
// Pre-swizzle W = [Wq*QSCALE | Wk | Wv] into bf16 B-fragment order:
// swz[((ksg*12 + tn)*64 + lane)*8 + j] = W'[k=ksg*32+(lane>>4)*8+j][n=tn*16+(lane&15)]
// ---------------------------------------------------------------------------
__global__ __launch_bounds__(256)
void wswz_kernel(const float* __restrict__ Wk, const float* __restrict__ Wq,
                 const float* __restrict__ Wv, unsigned short* __restrict__ swz)
{
    const int idx  = blockIdx.x * 256 + threadIdx.x;   // 0 .. 196607
    const int j    = idx & 7;
    const int lane = (idx >> 3) & 63;
    const int rest = idx >> 9;          // ksg*12 + tn
    const int tn   = rest % 12;
    const int ksg  = rest / 12;
    const int kk   = ksg * 32 + (lane >> 4) * 8 + j;
    const int n    = tn * 16 + (lane & 15);
    float val;
    if (n < 64)       val = Wq[kk * HDIM + n] * QSCALE;
    else if (n < 128) val = Wk[kk * HDIM + (n - 64)];
    else              val = Wv[kk * HDIM + (n - 128)];
    swz[idx] = f2bf(val);
}

// ---------------------------------------------------------------------------
// Fused projection v4: stage-once / compute-many, 16-row blocks.
// 1024 blocks x 256 thr (4 waves) = 4 blocks/CU co-resident: phase-1 HBM
// streaming of some blocks overlaps phase-2 MFMA of others.
// Phase 1: 16x1024 fp32 x -> bf16 -> LDS (16 independent float4 loads/thr).
// Phase 2: wave cq computes rows 0..15, cols cq*48..+48 over full K.
// ---------------------------------------------------------------------------
__global__ __launch_bounds__(256, 4)
void proj_kernel(const float* __restrict__ x, const unsigned short* __restrict__ swz,
                 unsigned short* __restrict__ q, unsigned short* __restrict__ k,
                 unsigned short* __restrict__ vt)
{
    __shared__ unsigned short xl[16][1032];   // 33 KB; +8 pad vs pow2 stride

    const int tid  = threadIdx.x;
    const int lane = tid & 63, wave = tid >> 6;
    const int quad = lane >> 4, l15 = lane & 15;
    const int cq   = wave;          // 48-col quarter
    const int m0   = blockIdx.x * 16;

    {   // phase 1: x slab -> LDS bf16
        const float* xb = x + (size_t)m0 * CDIM;
        float4 t[16];
        #pragma unroll
        for (int i = 0; i < 16; ++i)
            t[i] = *(const float4*)(xb + i * 1024 + tid * 4);   // all independent
        #pragma unroll
        for (int i = 0; i < 16; ++i) {
            const int o = i * 1024 + tid * 4;
            u16x4 p;
            p[0] = f2bf(t[i].x); p[1] = f2bf(t[i].y);
            p[2] = f2bf(t[i].z); p[3] = f2bf(t[i].w);
            *(u16x4*)&xl[o >> 10][o & 1023] = p;
        }
    }
    __syncthreads();

    // phase 2: 32 K-steps, B prefetched 1 ahead
    f32x4 acc[3] = {};
    const unsigned short* bp = swz + ((size_t)(cq * 3) * 64 + lane) * 8;
    s16x8 b0 = *(const s16x8*)(bp);
    s16x8 b1 = *(const s16x8*)(bp + 512);
    s16x8 b2 = *(const s16x8*)(bp + 1024);
    bp += 6144;

    #pragma unroll
    for (int ks = 0; ks < 32; ++ks) {
        s16x8 nb0, nb1, nb2;
        if (ks < 31) {
            nb0 = *(const s16x8*)(bp);
            nb1 = *(const s16x8*)(bp + 512);
            nb2 = *(const s16x8*)(bp + 1024);
            bp += 6144;
        }
        const s16x8 af = *(const s16x8*)&xl[l15][ks * 32 + quad * 8];
        acc[0] = __builtin_amdgcn_mfma_f32_16x16x32_bf16(af, b0, acc[0], 0, 0, 0);
        acc[1] = __builtin_amdgcn_mfma_f32_16x16x32_bf16(af, b1, acc[1], 0, 0, 0);
        acc[2] = __builtin_amdgcn_mfma_f32_16x16x32_bf16(af, b2, acc[2], 0, 0, 0);
        if (ks < 31) { b0 = nb0; b1 = nb1; b2 = nb2; }
    }

    // epilogue: C/D row = quad*4+r, col = cq*48 + t*16 + l15
    const int rowg = m0 + quad * 4;
    #pragma unroll
    for (int t = 0; t < 3; ++t) {
        const int n = cq * 48 + t * 16 + l15;
        if (n < 64) {
            #pragma unroll
            for (int r = 0; r < 4; ++r)
                q[(size_t)(rowg + r) * HDIM + n] = f2bf(acc[t][r]);
        } else if (n < 128) {
            #pragma unroll
            for (int r = 0; r < 4; ++r)
                k[(size_t)(rowg + r) * HDIM + (n - 64)] = f2bf(acc[t][r]);
        } else {
            const int h  = n - 128;
            const int bb = rowg >> 11, tl = rowg & 2047;
            u16x4 pv;
            #pragma unroll
            for (int r = 0; r < 4; ++r) pv[r] = f2bf(acc[t][r]);
            *(u16x4*)(vt + ((size_t)bb * HDIM + h) * TSEQ + tl) = pv;
        }
    }
}

// ---------------------------------------------------------------------------
// Flash attention pass 1, block-cooperative staged K/V, single LDS buffer
// with register prefetch. Block = (pair p, slice s in 0..7, batch b):
// 64-row q-tiles t=p and t=31-p sequentially (uniform work across blocks);
// slice s owns chunks c ≡ s (mod 8) of each tile (<= 4 per tile).
// 1024 blocks = 4/CU, all co-resident; staging barriers of one block hide
// under compute of the other three. LDS 25.6 KB/block.
// ---------------------------------------------------------------------------
__global__ __launch_bounds__(256, 4)
void attn_part(const unsigned short* __restrict__ q, const unsigned short* __restrict__ k,
               const unsigned short* __restrict__ vt, float* __restrict__ Opart,
               float* __restrict__ lpart)
{
    __shared__ unsigned short Kb[4096];        // 8 KB: chunk K, fragment order
    __shared__ unsigned short Vb[4096];        // 8 KB: chunk V^T, fragment order
    __shared__ unsigned short Pl[4][16][72];   // per-wave P transform (9.2 KB)

    const int tid  = threadIdx.x;
    const int lane = tid & 63, wave = tid >> 6;
    const int quad = lane >> 4, l15 = lane & 15;
    const int b    = blockIdx.y;
    const int p    = blockIdx.x >> 3;          // pair 0..15
    const int s    = blockIdx.x & 7;           // KV slice

    const unsigned short* qb  = q  + (size_t)b * TSEQ * HDIM;
    const unsigned short* kb  = k  + (size_t)b * TSEQ * HDIM;
    const unsigned short* vtb = vt + (size_t)b * HDIM * TSEQ;

    // staging map: thread covers groups g = tid, tid+256; g -> (r = g>>3,
    // cg = g&7); dest fragment-order elem ((ks*4+st)*64 + quad*16 + l15)*8
    // with st=r>>4, l15=r&15, ks=cg>>2, quad=cg&3.
    const int rs = tid >> 3, cgs = tid & 7;
    const int d0 = (((cgs >> 2) * 4 + (rs >> 4)) * 64 + (cgs & 3) * 16 + (rs & 15)) * 8;
    const int rs2 = rs + 32;
    const int d1 = (((cgs >> 2) * 4 + (rs2 >> 4)) * 64 + (cgs & 3) * 16 + (rs2 & 15)) * 8;

    for (int tsel = 0; tsel < 2; ++tsel) {
        const int t   = (tsel == 0) ? p : 31 - p;
        const int m0w = t * 64 + wave * 16;
        const int nt  = t + 1;                 // chunks 0..t

        // Q A-fragments for this tile
        const s16x8 aq0 = *(const s16x8*)(qb + (size_t)(m0w + l15) * HDIM + quad * 8);
        const s16x8 aq1 = *(const s16x8*)(qb + (size_t)(m0w + l15) * HDIM + 32 + quad * 8);

        f32x4 O[4] = {};
        float l_lane[4] = {0.f, 0.f, 0.f, 0.f};

        if (s < nt) {
            {   // stage first chunk
                const int n0 = s * 64;
                const s16x8 ka = *(const s16x8*)(kb + (size_t)(n0 + rs) * HDIM + cgs * 8);
                const s16x8 kc = *(const s16x8*)(kb + (size_t)(n0 + rs2) * HDIM + cgs * 8);
                const s16x8 va = *(const s16x8*)(vtb + (size_t)rs * TSEQ + n0 + cgs * 8);
                const s16x8 vc = *(const s16x8*)(vtb + (size_t)rs2 * TSEQ + n0 + cgs * 8);
                *(s16x8*)&Kb[d0] = ka; *(s16x8*)&Kb[d1] = kc;
                *(s16x8*)&Vb[d0] = va; *(s16x8*)&Vb[d1] = vc;
            }
            __syncthreads();

            for (int c = s; c < nt; c += 8) {
                const int cn = c + 8;
                const bool pref = cn < nt;     // block-uniform
                s16x8 ka, kc, va, vc;
                if (pref) {                     // next chunk into registers now
                    const int n0n = cn * 64;
                    ka = *(const s16x8*)(kb + (size_t)(n0n + rs) * HDIM + cgs * 8);
                    kc = *(const s16x8*)(kb + (size_t)(n0n + rs2) * HDIM + cgs * 8);
                    va = *(const s16x8*)(vtb + (size_t)rs * TSEQ + n0n + cgs * 8);
                    vc = *(const s16x8*)(vtb + (size_t)rs2 * TSEQ + n0n + cgs * 8);
                }

                // ---- compute chunk c ----
                f32x4 S[4] = {};
                #pragma unroll
                for (int st = 0; st < 4; ++st) {
                    const s16x8 k0 = *(const s16x8*)&Kb[(st * 64 + lane) * 8];
                    const s16x8 k1 = *(const s16x8*)&Kb[((4 + st) * 64 + lane) * 8];
                    S[st] = __builtin_amdgcn_mfma_f32_16x16x32_bf16(aq0, k0, S[st], 0, 0, 0);
                    S[st] = __builtin_amdgcn_mfma_f32_16x16x32_bf16(aq1, k1, S[st], 0, 0, 0);
                }

                const int n0 = c * 64;
                if (c == t) {                  // diagonal chunk: causal mask
                    const int rowbase = m0w + quad * 4;
                    #pragma unroll
                    for (int st = 0; st < 4; ++st) {
                        const int col = n0 + st * 16 + l15;
                        #pragma unroll
                        for (int r = 0; r < 4; ++r) {
                            const float pv = (col > rowbase + r) ? 0.f : exp2f(S[st][r]);
                            S[st][r] = pv;
                            l_lane[r] += pv;
                        }
                    }
                } else {                       // fully unmasked chunk
                    #pragma unroll
                    for (int st = 0; st < 4; ++st)
                        #pragma unroll
                        for (int r = 0; r < 4; ++r) {
                            const float pv = exp2f(S[st][r]);
                            S[st][r] = pv;
                            l_lane[r] += pv;
                        }
                }

                // P: C-layout -> A-layout via per-wave LDS slice
                #pragma unroll
                for (int st = 0; st < 4; ++st)
                    #pragma unroll
                    for (int r = 0; r < 4; ++r)
                        Pl[wave][quad * 4 + r][st * 16 + l15] = f2bf(S[st][r]);
                const s16x8 pa0 = *(const s16x8*)&Pl[wave][l15][quad * 8];
                const s16x8 pa1 = *(const s16x8*)&Pl[wave][l15][32 + quad * 8];

                // O += P V
                #pragma unroll
                for (int hst = 0; hst < 4; ++hst) {
                    const s16x8 v0 = *(const s16x8*)&Vb[(hst * 64 + lane) * 8];
                    const s16x8 v1 = *(const s16x8*)&Vb[((4 + hst) * 64 + lane) * 8];
                    O[hst] = __builtin_amdgcn_mfma_f32_16x16x32_bf16(pa0, v0, O[hst], 0, 0, 0);
                    O[hst] = __builtin_amdgcn_mfma_f32_16x16x32_bf16(pa1, v1, O[hst], 0, 0, 0);
                }

                if (pref) {
                    __syncthreads();           // all waves done reading Kb/Vb
                    *(s16x8*)&Kb[d0] = ka; *(s16x8*)&Kb[d1] = kc;
                    *(s16x8*)&Vb[d0] = va; *(s16x8*)&Vb[d1] = vc;
                    __syncthreads();
                }
            }
            __syncthreads();                   // before next tile restages
        }

        // l reduction across the 16 lanes of each row group
        #pragma unroll
        for (int off = 1; off < 16; off <<= 1)
            #pragma unroll
            for (int r = 0; r < 4; ++r)
                l_lane[r] += __shfl_xor(l_lane[r], off);

        // wave partial -> workspace
        const int ti16 = t * 4 + wave;
        const size_t pi = ((size_t)b * NTILE + ti16) * NSLC + s;
        #pragma unroll
        for (int hst = 0; hst < 4; ++hst)
            #pragma unroll
            for (int r = 0; r < 4; ++r)
                Opart[(pi * 16 + quad * 4 + r) * HDIM + hst * 16 + l15] = O[hst][r];
        if (l15 == 0) {
            #pragma unroll
            for (int r = 0; r < 4; ++r)
                lpart[pi * 16 + quad * 4 + r] = l_lane[r];
        }
    }
}

// ---------------------------------------------------------------------------
// Pass 2: out[row][c4..] = sum_s Opart / sum_s lpart.
// ---------------------------------------------------------------------------
__global__ __launch_bounds__(256)
void attn_combine(const float* __restrict__ Opart, const float* __restrict__ lpart,
                  float* __restrict__ out)
{
    const int g   = blockIdx.x * 256 + threadIdx.x;   // 0 .. 262143
    const int row = g >> 4;                           // 0 .. 16383
    const int c4  = (g & 15) << 2;
    const int b   = row >> 11, t = row & 2047;
    const int ti  = t >> 4,  r = t & 15;
    const size_t p0 = ((size_t)b * NTILE + ti) * NSLC;

    float4 acc = {0.f, 0.f, 0.f, 0.f};
    float lv = 0.f;
    #pragma unroll
    for (int s = 0; s < NSLC; ++s) {
        const float4 t4 = *(const float4*)(Opart + ((p0 + s) * 16 + r) * HDIM + c4);
        acc.x += t4.x; acc.y += t4.y; acc.z += t4.z; acc.w += t4.w;
        lv += lpart[(p0 + s) * 16 + r];
    }
    const float inv = 1.f / lv;
    float4 o = {acc.x * inv, acc.y * inv, acc.z * inv, acc.w * inv};
    *(float4*)(out + (size_t)row * HDIM + c4) = o;
}

// ---------------------------------------------------------------------------
extern "C" void kernel_launch(void* const* d_in, const int* in_sizes, int n_in,
                              void* d_out, int out_size, void* d_ws, size_t ws_size,
                              hipStream_t stream) {
    const float* x  = (const float*)d_in[0];
    const float* Wk = (const float*)d_in[1];
    const float* Wq = (const float*)d_in[2];
    const float* Wv = (const float*)d_in[3];
    float* out = (float*)d_out;

    // ws layout: swz | q | k | vt (bf16) then Opart | lpart (fp32). ~41 MB.
    unsigned short* swz = (unsigned short*)d_ws;            // 196608 elems
    unsigned short* qw  = swz + 196608;
    unsigned short* kw  = qw + (size_t)MROWS * HDIM;
    unsigned short* vtw = kw + (size_t)MROWS * HDIM;
    float* Opart = (float*)(vtw + (size_t)MROWS * HDIM);    // 8192*16*64 fp32
    float* lpart = Opart + (size_t)BATCH * NTILE * NSLC * 16 * HDIM;

    wswz_kernel<<<dim3(768), 256, 0, stream>>>(Wk, Wq, Wv, swz);
    proj_kernel<<<dim3(MROWS / 16), 256, 0, stream>>>(x, swz, qw, kw, vtw);
    attn_part<<<dim3(16 * NSLC, BATCH), 256, 0, stream>>>(qw, kw, vtw, Opart, lpart);
    attn_combine<<<dim3(MROWS * 16 / 256), 256, 0, stream>>>(Opart, lpart, out);
}

// Round 11
// 135.662 us; speedup vs baseline: 1.0324x; 1.0324x over previous
//
#include <hip/hip_runtime.h>
#include <math.h>

// B=8, T=2048, C=1024, H=64. bf16 MFMA proj + staged split-KV flash attention.
namespace {
constexpr int BATCH = 8;
constexpr int TSEQ  = 2048;
constexpr int CDIM  = 1024;
constexpr int HDIM  = 64;
constexpr int MROWS = BATCH * TSEQ;         // 16384
constexpr int NTILE = 128;                  // 16-row q-tiles per batch
constexpr int NSLC  = 8;                    // KV slices per q-tile
// fold softmax scale (1/8) AND log2(e) into Wq so softmax can use exp2
constexpr float QSCALE = 0.125f * 1.4426950408889634f;
}

typedef __attribute__((ext_vector_type(4))) float  f32x4;
typedef __attribute__((ext_vector_type(8))) short  s16x8;   // 8 bf16 (4 VGPRs)
typedef __attribute__((ext_vector_type(4))) unsigned short u16x4;

__device__ __forceinline__ unsigned short f2bf(float f) {
    union { float f; unsigned u; } c{f};
    unsigned r = c.u + 0x7FFFu + ((c.u >> 16) & 1u);   // RNE
    return (unsigned short)(r >> 16);
}
__device__ __forceinline__ float bf2f(unsigned short h) {
    union { unsigned u; float f; } c;
    c.u = (unsigned)h << 16;
    return c.f;
}

// ---------------------------------------------------------------------------
// Pre-swizzle W = [Wq*QSCALE | Wk | Wv] into bf16 B-fragment order:
// swz[((ksg*12 + tn)*64 + lane)*8 + j] = W'[k=ksg*32+(lane>>4)*8+j][n=tn*16+(lane&15)]
// ---------------------------------------------------------------------------
__global__ __launch_bounds__(256)
void wswz_kernel(const float* __restrict__ Wk, const float* __restrict__ Wq,
                 const float* __restrict__ Wv, unsigned short* __restrict__ swz)
{
    const int idx  = blockIdx.x * 256 + threadIdx.x;   // 0 .. 196607
    const int j    = idx & 7;
    const int lane = (idx >> 3) & 63;
    const int rest = idx >> 9;          // ksg*12 + tn
    const int tn   = rest % 12;
    const int ksg  = rest / 12;
    const int kk   = ksg * 32 + (lane >> 4) * 8 + j;
    const int n    = tn * 16 + (lane & 15);
    float val;
    if (n < 64)       val = Wq[kk * HDIM + n] * QSCALE;
    else if (n < 128) val = Wk[kk * HDIM + (n - 64)];
    else              val = Wv[kk * HDIM + (n - 128)];
    swz[idx] = f2bf(val);
}

// ---------------------------------------------------------------------------
// Fused projection v4 (unchanged from round 10): stage-once / compute-many.
// 1024 blocks x 256 thr (4 waves) = 4 blocks/CU co-resident.
// ---------------------------------------------------------------------------
__global__ __launch_bounds__(256, 4)
void proj_kernel(const float* __restrict__ x, const unsigned short* __restrict__ swz,
                 unsigned short* __restrict__ q, unsigned short* __restrict__ k,
                 unsigned short* __restrict__ vt)
{
    __shared__ unsigned short xl[16][1032];   // 33 KB; +8 pad vs pow2 stride

    const int tid  = threadIdx.x;
    const int lane = tid & 63, wave = tid >> 6;
    const int quad = lane >> 4, l15 = lane & 15;
    const int cq   = wave;          // 48-col quarter
    const int m0   = blockIdx.x * 16;

    {   // phase 1: x slab -> LDS bf16
        const float* xb = x + (size_t)m0 * CDIM;
        float4 t[16];
        #pragma unroll
        for (int i = 0; i < 16; ++i)
            t[i] = *(const float4*)(xb + i * 1024 + tid * 4);   // all independent
        #pragma unroll
        for (int i = 0; i < 16; ++i) {
            const int o = i * 1024 + tid * 4;
            u16x4 p;
            p[0] = f2bf(t[i].x); p[1] = f2bf(t[i].y);
            p[2] = f2bf(t[i].z); p[3] = f2bf(t[i].w);
            *(u16x4*)&xl[o >> 10][o & 1023] = p;
        }
    }
    __syncthreads();

    // phase 2: 32 K-steps, B prefetched 1 ahead
    f32x4 acc[3] = {};
    const unsigned short* bp = swz + ((size_t)(cq * 3) * 64 + lane) * 8;
    s16x8 b0 = *(const s16x8*)(bp);
    s16x8 b1 = *(const s16x8*)(bp + 512);
    s16x8 b2 = *(const s16x8*)(bp + 1024);
    bp += 6144;

    #pragma unroll
    for (int ks = 0; ks < 32; ++ks) {
        s16x8 nb0, nb1, nb2;
        if (ks < 31) {
            nb0 = *(const s16x8*)(bp);
            nb1 = *(const s16x8*)(bp + 512);
            nb2 = *(const s16x8*)(bp + 1024);
            bp += 6144;
        }
        const s16x8 af = *(const s16x8*)&xl[l15][ks * 32 + quad * 8];
        acc[0] = __builtin_amdgcn_mfma_f32_16x16x32_bf16(af, b0, acc[0], 0, 0, 0);
        acc[1] = __builtin_amdgcn_mfma_f32_16x16x32_bf16(af, b1, acc[1], 0, 0, 0);
        acc[2] = __builtin_amdgcn_mfma_f32_16x16x32_bf16(af, b2, acc[2], 0, 0, 0);
        if (ks < 31) { b0 = nb0; b1 = nb1; b2 = nb2; }
    }

    // epilogue: C/D row = quad*4+r, col = cq*48 + t*16 + l15
    const int rowg = m0 + quad * 4;
    #pragma unroll
    for (int t = 0; t < 3; ++t) {
        const int n = cq * 48 + t * 16 + l15;
        if (n < 64) {
            #pragma unroll
            for (int r = 0; r < 4; ++r)
                q[(size_t)(rowg + r) * HDIM + n] = f2bf(acc[t][r]);
        } else if (n < 128) {
            #pragma unroll
            for (int r = 0; r < 4; ++r)
                k[(size_t)(rowg + r) * HDIM + (n - 64)] = f2bf(acc[t][r]);
        } else {
            const int h  = n - 128;
            const int bb = rowg >> 11, tl = rowg & 2047;
            u16x4 pv;
            #pragma unroll
            for (int r = 0; r < 4; ++r) pv[r] = f2bf(acc[t][r]);
            *(u16x4*)(vt + ((size_t)bb * HDIM + h) * TSEQ + tl) = pv;
        }
    }
}

// ---------------------------------------------------------------------------
// Flash attention pass 1, block-cooperative staged K/V, single LDS buffer,
// INTERLEAVED staging barriers: per chunk, S -> bar -> write next-K ->
// softmax/P/PV -> bar -> write next-V. Staging writes overlap compute of
// other waves instead of a dead barrier-to-barrier window.
// Block = (pair p, slice s in 0..7, batch b): q-tiles t=p and t=31-p,
// slice s owns chunks c ≡ s (mod 8). 1024 blocks = 4/CU, all co-resident.
// Partials stored bf16 (O) + fp32 (l).
// ---------------------------------------------------------------------------
__global__ __launch_bounds__(256, 4)
void attn_part(const unsigned short* __restrict__ q, const unsigned short* __restrict__ k,
               const unsigned short* __restrict__ vt, unsigned short* __restrict__ Opart,
               float* __restrict__ lpart)
{
    __shared__ unsigned short Kb[4096];        // 8 KB: chunk K, fragment order
    __shared__ unsigned short Vb[4096];        // 8 KB: chunk V^T, fragment order
    __shared__ unsigned short Pl[4][16][72];   // per-wave P transform (9.2 KB)

    const int tid  = threadIdx.x;
    const int lane = tid & 63, wave = tid >> 6;
    const int quad = lane >> 4, l15 = lane & 15;
    const int b    = blockIdx.y;
    const int p    = blockIdx.x >> 3;          // pair 0..15
    const int s    = blockIdx.x & 7;           // KV slice

    const unsigned short* qb  = q  + (size_t)b * TSEQ * HDIM;
    const unsigned short* kb  = k  + (size_t)b * TSEQ * HDIM;
    const unsigned short* vtb = vt + (size_t)b * HDIM * TSEQ;

    // staging map: thread covers groups g = tid, tid+256; g -> (r = g>>3,
    // cg = g&7); dest fragment-order elem ((ks*4+st)*64 + quad*16 + l15)*8
    // with st=r>>4, l15=r&15, ks=cg>>2, quad=cg&3.
    const int rs = tid >> 3, cgs = tid & 7;
    const int d0 = (((cgs >> 2) * 4 + (rs >> 4)) * 64 + (cgs & 3) * 16 + (rs & 15)) * 8;
    const int rs2 = rs + 32;
    const int d1 = (((cgs >> 2) * 4 + (rs2 >> 4)) * 64 + (cgs & 3) * 16 + (rs2 & 15)) * 8;

    for (int tsel = 0; tsel < 2; ++tsel) {
        const int t   = (tsel == 0) ? p : 31 - p;
        const int m0w = t * 64 + wave * 16;
        const int nt  = t + 1;                 // chunks 0..t

        // Q A-fragments for this tile
        const s16x8 aq0 = *(const s16x8*)(qb + (size_t)(m0w + l15) * HDIM + quad * 8);
        const s16x8 aq1 = *(const s16x8*)(qb + (size_t)(m0w + l15) * HDIM + 32 + quad * 8);

        f32x4 O[4] = {};
        float l_lane[4] = {0.f, 0.f, 0.f, 0.f};

        if (s < nt) {                          // block-uniform branch
            {   // stage first chunk
                const int n0 = s * 64;
                const s16x8 ka = *(const s16x8*)(kb + (size_t)(n0 + rs) * HDIM + cgs * 8);
                const s16x8 kc = *(const s16x8*)(kb + (size_t)(n0 + rs2) * HDIM + cgs * 8);
                const s16x8 va = *(const s16x8*)(vtb + (size_t)rs * TSEQ + n0 + cgs * 8);
                const s16x8 vc = *(const s16x8*)(vtb + (size_t)rs2 * TSEQ + n0 + cgs * 8);
                *(s16x8*)&Kb[d0] = ka; *(s16x8*)&Kb[d1] = kc;
                *(s16x8*)&Vb[d0] = va; *(s16x8*)&Vb[d1] = vc;
            }
            __syncthreads();

            for (int c = s; c < nt; c += 8) {
                const bool pref = (c + 8) < nt;   // block-uniform
                s16x8 ka, kc, va, vc;
                if (pref) {                        // next chunk into registers now
                    const int n0n = (c + 8) * 64;
                    ka = *(const s16x8*)(kb + (size_t)(n0n + rs) * HDIM + cgs * 8);
                    kc = *(const s16x8*)(kb + (size_t)(n0n + rs2) * HDIM + cgs * 8);
                    va = *(const s16x8*)(vtb + (size_t)rs * TSEQ + n0n + cgs * 8);
                    vc = *(const s16x8*)(vtb + (size_t)rs2 * TSEQ + n0n + cgs * 8);
                }

                // ---- S = Q K^T from Kb ----
                f32x4 S[4] = {};
                #pragma unroll
                for (int st = 0; st < 4; ++st) {
                    const s16x8 k0 = *(const s16x8*)&Kb[(st * 64 + lane) * 8];
                    const s16x8 k1 = *(const s16x8*)&Kb[((4 + st) * 64 + lane) * 8];
                    S[st] = __builtin_amdgcn_mfma_f32_16x16x32_bf16(aq0, k0, S[st], 0, 0, 0);
                    S[st] = __builtin_amdgcn_mfma_f32_16x16x32_bf16(aq1, k1, S[st], 0, 0, 0);
                }
                __syncthreads();                   // bar1: all waves done with Kb
                if (pref) { *(s16x8*)&Kb[d0] = ka; *(s16x8*)&Kb[d1] = kc; }

                // ---- softmax (no-max, exp2 domain) ----
                const int n0 = c * 64;
                if (c == t) {                      // diagonal chunk: causal mask
                    const int rowbase = m0w + quad * 4;
                    #pragma unroll
                    for (int st = 0; st < 4; ++st) {
                        const int col = n0 + st * 16 + l15;
                        #pragma unroll
                        for (int r = 0; r < 4; ++r) {
                            const float pv = (col > rowbase + r) ? 0.f : exp2f(S[st][r]);
                            S[st][r] = pv;
                            l_lane[r] += pv;
                        }
                    }
                } else {
                    #pragma unroll
                    for (int st = 0; st < 4; ++st)
                        #pragma unroll
                        for (int r = 0; r < 4; ++r) {
                            const float pv = exp2f(S[st][r]);
                            S[st][r] = pv;
                            l_lane[r] += pv;
                        }
                }

                // P: C-layout -> A-layout via per-wave LDS slice
                #pragma unroll
                for (int st = 0; st < 4; ++st)
                    #pragma unroll
                    for (int r = 0; r < 4; ++r)
                        Pl[wave][quad * 4 + r][st * 16 + l15] = f2bf(S[st][r]);
                const s16x8 pa0 = *(const s16x8*)&Pl[wave][l15][quad * 8];
                const s16x8 pa1 = *(const s16x8*)&Pl[wave][l15][32 + quad * 8];

                // ---- O += P V from Vb ----
                #pragma unroll
                for (int hst = 0; hst < 4; ++hst) {
                    const s16x8 v0 = *(const s16x8*)&Vb[(hst * 64 + lane) * 8];
                    const s16x8 v1 = *(const s16x8*)&Vb[((4 + hst) * 64 + lane) * 8];
                    O[hst] = __builtin_amdgcn_mfma_f32_16x16x32_bf16(pa0, v0, O[hst], 0, 0, 0);
                    O[hst] = __builtin_amdgcn_mfma_f32_16x16x32_bf16(pa1, v1, O[hst], 0, 0, 0);
                }
                __syncthreads();                   // bar2: Vb free, Kb writes fenced
                if (pref) { *(s16x8*)&Vb[d0] = va; *(s16x8*)&Vb[d1] = vc; }
                // next S reads Kb (fenced by bar2); next PV reads Vb (fenced
                // by next iteration's bar1).
            }
            __syncthreads();                       // before next tile restages
        }

        // l reduction across the 16 lanes of each row group
        #pragma unroll
        for (int off = 1; off < 16; off <<= 1)
            #pragma unroll
            for (int r = 0; r < 4; ++r)
                l_lane[r] += __shfl_xor(l_lane[r], off);

        // wave partial -> workspace (O as bf16; l fp32)
        const int ti16 = t * 4 + wave;
        const size_t pi = ((size_t)b * NTILE + ti16) * NSLC + s;
        #pragma unroll
        for (int hst = 0; hst < 4; ++hst)
            #pragma unroll
            for (int r = 0; r < 4; ++r)
                Opart[(pi * 16 + quad * 4 + r) * HDIM + hst * 16 + l15] = f2bf(O[hst][r]);
        if (l15 == 0) {
            #pragma unroll
            for (int r = 0; r < 4; ++r)
                lpart[pi * 16 + quad * 4 + r] = l_lane[r];
        }
    }
}

// ---------------------------------------------------------------------------
// Pass 2: out[row][c4..] = sum_s Opart(bf16) / sum_s lpart.
// ---------------------------------------------------------------------------
__global__ __launch_bounds__(256)
void attn_combine(const unsigned short* __restrict__ Opart, const float* __restrict__ lpart,
                  float* __restrict__ out)
{
    const int g   = blockIdx.x * 256 + threadIdx.x;   // 0 .. 262143
    const int row = g >> 4;                           // 0 .. 16383
    const int c4  = (g & 15) << 2;
    const int b   = row >> 11, t = row & 2047;
    const int ti  = t >> 4,  r = t & 15;
    const size_t p0 = ((size_t)b * NTILE + ti) * NSLC;

    float acc[4] = {0.f, 0.f, 0.f, 0.f};
    float lv = 0.f;
    #pragma unroll
    for (int s = 0; s < NSLC; ++s) {
        const u16x4 t4 = *(const u16x4*)(Opart + ((p0 + s) * 16 + r) * HDIM + c4);
        #pragma unroll
        for (int j = 0; j < 4; ++j) acc[j] += bf2f(t4[j]);
        lv += lpart[(p0 + s) * 16 + r];
    }
    const float inv = 1.f / lv;
    float4 o = {acc[0] * inv, acc[1] * inv, acc[2] * inv, acc[3] * inv};
    *(float4*)(out + (size_t)row * HDIM + c4) = o;
}

// ---------------------------------------------------------------------------
extern "C" void kernel_launch(void* const* d_in, const int* in_sizes, int n_in,
                              void* d_out, int out_size, void* d_ws, size_t ws_size,
                              hipStream_t stream) {
    const float* x  = (const float*)d_in[0];
    const float* Wk = (const float*)d_in[1];
    const float* Wq = (const float*)d_in[2];
    const float* Wv = (const float*)d_in[3];
    float* out = (float*)d_out;

    // ws layout: swz | q | k | vt | Opart (bf16) then lpart (fp32). ~24 MB.
    unsigned short* swz = (unsigned short*)d_ws;            // 196608 elems
    unsigned short* qw  = swz + 196608;
    unsigned short* kw  = qw + (size_t)MROWS * HDIM;
    unsigned short* vtw = kw + (size_t)MROWS * HDIM;
    unsigned short* Opart = vtw + (size_t)MROWS * HDIM;     // 8192*16*64 bf16
    float* lpart = (float*)(Opart + (size_t)BATCH * NTILE * NSLC * 16 * HDIM);

    wswz_kernel<<<dim3(768), 256, 0, stream>>>(Wk, Wq, Wv, swz);
    proj_kernel<<<dim3(MROWS / 16), 256, 0, stream>>>(x, swz, qw, kw, vtw);
    attn_part<<<dim3(16 * NSLC, BATCH), 256, 0, stream>>>(qw, kw, vtw, Opart, lpart);
    attn_combine<<<dim3(MROWS * 16 / 256), 256, 0, stream>>>(Opart, lpart, out);
}